// Round 1
// baseline (277.217 us; speedup 1.0000x reference)
//
#include <hip/hip_runtime.h>

#define B_SZ 4096
#define T_SZ 64
#define F_SZ 512
#define H_SZ 64
#define G_SZ 256   // 4*H
#define BR 16      // batch rows per block
#define TC 8       // timesteps per chunk
#define NCHUNK (T_SZ / TC)   // 8
#define KT 64      // K tile for xg GEMM
#define NKT (F_SZ / KT)      // 8

typedef _Float16 f16x8 __attribute__((ext_vector_type(8)));
typedef float f32x4 __attribute__((ext_vector_type(4)));

static_assert(sizeof(f16x8) == 16, "f16x8 must be 16B");

__device__ __forceinline__ float fast_rcp(float x) { return __builtin_amdgcn_rcpf(x); }
__device__ __forceinline__ float sigm(float x) { return fast_rcp(1.0f + __expf(-x)); }
__device__ __forceinline__ float tanh_f(float x) {
  x = fminf(15.0f, fmaxf(-15.0f, x));   // avoid exp overflow -> NaN; tanh saturated anyway
  float e = __expf(2.0f * x);
  return (e - 1.0f) * fast_rcp(e + 1.0f);
}

// Fused LSTM: each block owns BR=16 batch rows for all T=64 steps.
// Per chunk of TC=8 steps: (A) xg = x@Wih^T via fp16 MFMA, M=128 (tile m-index = step,
// rows within = batch row), accumulators stay in registers; (B) 8 scan steps:
// gates = xg_acc + h@Whh^T (2 chained MFMAs, Whh B-frags pinned in registers) + bias,
// activations + c/h update fully in-register (wave w owns h-units [16w,16w+16)).
__global__ __launch_bounds__(256, 1)
void lstm_fused(const float* __restrict__ x, const float* __restrict__ Wih,
                const float* __restrict__ Whh, const float* __restrict__ bih,
                const float* __restrict__ bhh, const float* __restrict__ Wfc,
                const float* __restrict__ bfc, float* __restrict__ out)
{
  // 72-element row stride (144B = 36 banks): breaks 128B-stride 16-way bank conflicts,
  // keeps every f16x8 access 16B-aligned (144 = 9*16).
  __shared__ __align__(16) _Float16 Alds[128][72];     // x chunk, m = s*16 + r
  __shared__ __align__(16) _Float16 Blds[256][72];     // weight tile, [n][k]
  __shared__ __align__(16) _Float16 hbuf[2][16][72];   // h double buffer, [row][unit]
  __shared__ float h32[16][64];                        // final h in fp32

  const int tid  = threadIdx.x;
  const int wv   = tid >> 6;        // wave 0..3
  const int lane = tid & 63;
  const int ln   = lane & 15;
  const int kg   = lane >> 4;       // k-group 0..3
  const int br0  = blockIdx.x * BR;

  // zero h0
  for (int i = tid; i < 16 * 72; i += 256) (&hbuf[0][0][0])[i] = (_Float16)0.0f;

  // Stage Whh (fp32 [256][64]) -> Blds[n][k] as fp16 (coalesced-ish; L2 resident)
  #pragma unroll
  for (int it = 0; it < 4; ++it) {
    const int n  = it * 64 + (tid >> 2);
    const int kl = (tid & 3) * 16;
    const float4* src = (const float4*)(Whh + (size_t)n * H_SZ + kl);
    float4 v0 = src[0], v1 = src[1], v2 = src[2], v3 = src[3];
    f16x8 h0, h1;
    h0[0] = (_Float16)v0.x; h0[1] = (_Float16)v0.y; h0[2] = (_Float16)v0.z; h0[3] = (_Float16)v0.w;
    h0[4] = (_Float16)v1.x; h0[5] = (_Float16)v1.y; h0[6] = (_Float16)v1.z; h0[7] = (_Float16)v1.w;
    h1[0] = (_Float16)v2.x; h1[1] = (_Float16)v2.y; h1[2] = (_Float16)v2.z; h1[3] = (_Float16)v2.w;
    h1[4] = (_Float16)v3.x; h1[5] = (_Float16)v3.y; h1[6] = (_Float16)v3.z; h1[7] = (_Float16)v3.w;
    *(f16x8*)&Blds[n][kl]     = h0;
    *(f16x8*)&Blds[n][kl + 8] = h1;
  }
  __syncthreads();

  // Whh B-fragments pinned in registers for all 64 steps.
  // B[k][n] = Whh[n][k]; lane holds k = kg*8+j (+32*k2), n = ntile*16 + ln, ntile = g*4+wv.
  f16x8 whhf[4][2];
  #pragma unroll
  for (int g = 0; g < 4; ++g)
    #pragma unroll
    for (int k2 = 0; k2 < 2; ++k2)
      whhf[g][k2] = *(const f16x8*)&Blds[(g * 4 + wv) * 16 + ln][kg * 8 + k2 * 32];

  const int u = wv * 16 + ln;   // h-unit owned by this lane
  float bsum[4];
  #pragma unroll
  for (int g = 0; g < 4; ++g) bsum[g] = bih[g * 64 + u] + bhh[g * 64 + u];

  f32x4 cst = {0.0f, 0.0f, 0.0f, 0.0f};   // c state: rows kg*4+r, unit u

  for (int cc = 0; cc < NCHUNK; ++cc) {
    f32x4 acc[TC][4];
    #pragma unroll
    for (int s = 0; s < TC; ++s)
      #pragma unroll
      for (int g = 0; g < 4; ++g) acc[s][g] = (f32x4){0.0f, 0.0f, 0.0f, 0.0f};

    // ---- Phase A: xg accumulation over K = 512 in tiles of 64 ----
    for (int kk = 0; kk < NKT; ++kk) {
      __syncthreads();   // previous tile's fragment reads complete
      // stage A: x[br0+r][cc*8+s][kk*64 .. +64] -> Alds[s*16+r][k] fp16
      {
        const int aRow = tid >> 1;
        const int s = aRow >> 4, r = aRow & 15;
        const int hf = tid & 1;
        const float* src = x + (size_t)(br0 + r) * (T_SZ * F_SZ)
                             + (size_t)(cc * TC + s) * F_SZ + kk * KT + hf * 32;
        float4 v[8];
        #pragma unroll
        for (int j = 0; j < 8; ++j) v[j] = ((const float4*)src)[j];
        #pragma unroll
        for (int j = 0; j < 4; ++j) {
          const float4 a = v[2 * j], b = v[2 * j + 1];
          f16x8 hv;
          hv[0] = (_Float16)a.x; hv[1] = (_Float16)a.y; hv[2] = (_Float16)a.z; hv[3] = (_Float16)a.w;
          hv[4] = (_Float16)b.x; hv[5] = (_Float16)b.y; hv[6] = (_Float16)b.z; hv[7] = (_Float16)b.w;
          *(f16x8*)&Alds[aRow][hf * 32 + j * 8] = hv;
        }
      }
      // stage B: Wih[n][kk*64 + k] -> Blds[n][k] fp16 (L2/L3 resident)
      #pragma unroll
      for (int it = 0; it < 4; ++it) {
        const int n  = it * 64 + (tid >> 2);
        const int kl = (tid & 3) * 16;
        const float4* src = (const float4*)(Wih + (size_t)n * F_SZ + kk * KT + kl);
        float4 v0 = src[0], v1 = src[1], v2 = src[2], v3 = src[3];
        f16x8 h0, h1;
        h0[0] = (_Float16)v0.x; h0[1] = (_Float16)v0.y; h0[2] = (_Float16)v0.z; h0[3] = (_Float16)v0.w;
        h0[4] = (_Float16)v1.x; h0[5] = (_Float16)v1.y; h0[6] = (_Float16)v1.z; h0[7] = (_Float16)v1.w;
        h1[0] = (_Float16)v2.x; h1[1] = (_Float16)v2.y; h1[2] = (_Float16)v2.z; h1[3] = (_Float16)v2.w;
        h1[4] = (_Float16)v3.x; h1[5] = (_Float16)v3.y; h1[6] = (_Float16)v3.z; h1[7] = (_Float16)v3.w;
        *(f16x8*)&Blds[n][kl]     = h0;
        *(f16x8*)&Blds[n][kl + 8] = h1;
      }
      __syncthreads();

      // B-frags once per tile, reused across all 8 M-tiles
      f16x8 bfr[4][2];
      #pragma unroll
      for (int g = 0; g < 4; ++g)
        #pragma unroll
        for (int k2 = 0; k2 < 2; ++k2)
          bfr[g][k2] = *(const f16x8*)&Blds[(g * 4 + wv) * 16 + ln][kg * 8 + k2 * 32];

      #pragma unroll
      for (int s = 0; s < TC; ++s) {
        f16x8 af0 = *(const f16x8*)&Alds[s * 16 + ln][kg * 8];
        f16x8 af1 = *(const f16x8*)&Alds[s * 16 + ln][kg * 8 + 32];
        #pragma unroll
        for (int g = 0; g < 4; ++g) {
          acc[s][g] = __builtin_amdgcn_mfma_f32_16x16x32_f16(af0, bfr[g][0], acc[s][g], 0, 0, 0);
          acc[s][g] = __builtin_amdgcn_mfma_f32_16x16x32_f16(af1, bfr[g][1], acc[s][g], 0, 0, 0);
        }
      }
    }

    // ---- Phase B: 8 sequential scan steps ----
    #pragma unroll
    for (int s = 0; s < TC; ++s) {
      const int st = cc * TC + s;
      const _Float16* hr = &hbuf[st & 1][0][0];
      f16x8 ah0 = *(const f16x8*)(hr + ln * 72 + kg * 8);
      f16x8 ah1 = *(const f16x8*)(hr + ln * 72 + kg * 8 + 32);
      f32x4 gf[4];
      #pragma unroll
      for (int g = 0; g < 4; ++g) {
        gf[g] = acc[s][g];
        gf[g] = __builtin_amdgcn_mfma_f32_16x16x32_f16(ah0, whhf[g][0], gf[g], 0, 0, 0);
        gf[g] = __builtin_amdgcn_mfma_f32_16x16x32_f16(ah1, whhf[g][1], gf[g], 0, 0, 0);
      }
      _Float16* hw = &hbuf[(st + 1) & 1][0][0];
      #pragma unroll
      for (int r = 0; r < 4; ++r) {
        const float iv = sigm(gf[0][r] + bsum[0]);
        const float fv = sigm(gf[1][r] + bsum[1]);
        const float gv = tanh_f(gf[2][r] + bsum[2]);
        const float ov = sigm(gf[3][r] + bsum[3]);
        const float cn = fv * cst[r] + iv * gv;
        cst[r] = cn;
        const float hn = ov * tanh_f(cn);
        hw[(kg * 4 + r) * 72 + u] = (_Float16)hn;
        if (cc == NCHUNK - 1 && s == TC - 1) h32[kg * 4 + r][u] = hn;
      }
      __syncthreads();   // h writes visible before next step's reads (double-buffered)
    }
  }

  // ---- FC head: out[row][j] = b_fc[j] + sum_u h[row][u] * Wfc[j][u] ----
  if (tid < 32) {
    const int r = tid >> 1, j = tid & 1;
    float a = bfc[j];
    #pragma unroll
    for (int uu = 0; uu < 64; ++uu) a += h32[r][uu] * Wfc[j * 64 + uu];
    out[(size_t)(br0 + r) * 2 + j] = a;
  }
}

extern "C" void kernel_launch(void* const* d_in, const int* in_sizes, int n_in,
                              void* d_out, int out_size, void* d_ws, size_t ws_size,
                              hipStream_t stream) {
  const float* x   = (const float*)d_in[0];
  const float* Wih = (const float*)d_in[1];
  const float* Whh = (const float*)d_in[2];
  const float* bih = (const float*)d_in[3];
  const float* bhh = (const float*)d_in[4];
  const float* Wfc = (const float*)d_in[5];
  const float* bfc = (const float*)d_in[6];
  float* out = (float*)d_out;
  lstm_fused<<<dim3(B_SZ / BR), dim3(256), 0, stream>>>(x, Wih, Whh, bih, bhh, Wfc, bfc, out);
}

// Round 2
// 255.840 us; speedup vs baseline: 1.0836x; 1.0836x over previous
//
#include <hip/hip_runtime.h>

#define B_SZ 4096
#define T_SZ 64
#define F_SZ 512
#define H_SZ 64
#define BR 8                  // batch rows per block -> 512 blocks, 2 blocks/CU
#define TC 16                 // timesteps per chunk
#define NCHUNK (T_SZ / TC)    // 4
#define KH 256                // K-half staged in LDS per barrier
#define AXS 264               // Ax row stride in fp16 elems (528B, 16B-aligned)

typedef _Float16 f16x8 __attribute__((ext_vector_type(8)));
typedef float f32x4 __attribute__((ext_vector_type(4)));

static_assert(sizeof(f16x8) == 16, "f16x8 must be 16B");

__device__ __forceinline__ float fast_rcp(float x) { return __builtin_amdgcn_rcpf(x); }
__device__ __forceinline__ float sigm(float x) { return fast_rcp(1.0f + __expf(-x)); }
__device__ __forceinline__ float tanh_f(float x) {
  x = fminf(15.0f, fmaxf(-15.0f, x));
  float e = __expf(2.0f * x);
  return (e - 1.0f) * fast_rcp(e + 1.0f);
}
__device__ __forceinline__ f16x8 cvt8(float4 a, float4 b) {
  f16x8 h;
  h[0] = (_Float16)a.x; h[1] = (_Float16)a.y; h[2] = (_Float16)a.z; h[3] = (_Float16)a.w;
  h[4] = (_Float16)b.x; h[5] = (_Float16)b.y; h[6] = (_Float16)b.z; h[7] = (_Float16)b.w;
  return h;
}

// 512 blocks x 256 threads, 2 blocks/CU. Each block: 8 batch rows, all 64 steps.
// Phase A per chunk (16 steps): stage x fp16 in LDS per K-half (1 barrier covers 4
// K-tiles of MFMA); Wih B-frags loaded DIRECT global->reg (no LDS: zero reuse across
// waves). M-tile = 2 steps x 8 rows. Phase B: per-step parity (kg-half) owns gates;
// c and h flow through LDS across the per-step barrier.
__global__ __launch_bounds__(256, 2)
void lstm_fused(const float* __restrict__ x, const float* __restrict__ Wih,
                const float* __restrict__ Whh, const float* __restrict__ bih,
                const float* __restrict__ bhh, const float* __restrict__ Wfc,
                const float* __restrict__ bfc, float* __restrict__ out)
{
  __shared__ __align__(16) _Float16 Ax[128][AXS];    // x chunk-half, mrow = s*8+r
  __shared__ __align__(16) _Float16 hbuf[2][8][72];  // h double buffer
  __shared__ float cb[8][64];                        // c state (LDS-resident)
  __shared__ float h32[8][64];                       // final h fp32

  const int tid  = threadIdx.x;
  const int wv   = tid >> 6;
  const int lane = tid & 63;
  const int ln   = lane & 15;
  const int kg   = lane >> 4;
  const int br0  = blockIdx.x * BR;
  const int u    = wv * 16 + ln;     // h-unit column owned by this lane

  for (int i = tid; i < 8 * 72; i += 256) (&hbuf[0][0][0])[i] = (_Float16)0.0f;
  for (int i = tid; i < 8 * 64; i += 256) (&cb[0][0])[i] = 0.0f;

  // Whh B-fragments pinned in registers for all 64 steps (direct global->reg, fp16)
  f16x8 whhf[4][2];
  #pragma unroll
  for (int g = 0; g < 4; ++g)
    #pragma unroll
    for (int k2 = 0; k2 < 2; ++k2) {
      const float4* p = (const float4*)(Whh + (size_t)((g * 4 + wv) * 16 + ln) * H_SZ
                                            + kg * 8 + k2 * 32);
      whhf[g][k2] = cvt8(p[0], p[1]);
    }

  float bsum[4];
  #pragma unroll
  for (int g = 0; g < 4; ++g) bsum[g] = bih[g * 64 + u] + bhh[g * 64 + u];

  // x staging geometry: 2 threads per mrow, 128 consecutive floats each
  const int mrow = tid >> 1;           // 0..127 = s*8 + r
  const int sA   = mrow >> 3, rA = mrow & 7;
  const int colA = (tid & 1) * 128;    // float offset within K-half
  const float* xbase = x + (size_t)(br0 + rA) * (T_SZ * F_SZ) + colA;

  for (int cc = 0; cc < NCHUNK; ++cc) {
    f32x4 acc[8][4];
    #pragma unroll
    for (int t = 0; t < 8; ++t)
      #pragma unroll
      for (int g = 0; g < 4; ++g) acc[t][g] = (f32x4){0.0f, 0.0f, 0.0f, 0.0f};

    #pragma unroll
    for (int khalf = 0; khalf < 2; ++khalf) {
      __syncthreads();   // prior reads of Ax / phase B complete
      {
        const float* src = xbase + (size_t)(cc * TC + sA) * F_SZ + khalf * KH;
        _Float16* dst = &Ax[mrow][colA];
        #pragma unroll
        for (int j = 0; j < 8; ++j) {
          float4 a = ((const float4*)src)[j * 4 + 0];
          float4 b = ((const float4*)src)[j * 4 + 1];
          float4 c = ((const float4*)src)[j * 4 + 2];
          float4 d = ((const float4*)src)[j * 4 + 3];
          *(f16x8*)(dst + j * 16)     = cvt8(a, b);
          *(f16x8*)(dst + j * 16 + 8) = cvt8(c, d);
        }
      }
      __syncthreads();

      #pragma unroll 2
      for (int kk = 0; kk < 4; ++kk) {
        const int kb = khalf * KH + kk * 64;
        f16x8 bfr[4][2];
        #pragma unroll
        for (int g = 0; g < 4; ++g)
          #pragma unroll
          for (int k2 = 0; k2 < 2; ++k2) {
            const float4* p = (const float4*)(Wih + (size_t)((g * 4 + wv) * 16 + ln) * F_SZ
                                                  + kb + kg * 8 + k2 * 32);
            bfr[g][k2] = cvt8(p[0], p[1]);
          }
        #pragma unroll
        for (int t = 0; t < 8; ++t) {
          f16x8 af0 = *(const f16x8*)&Ax[t * 16 + ln][kk * 64 + kg * 8];
          f16x8 af1 = *(const f16x8*)&Ax[t * 16 + ln][kk * 64 + kg * 8 + 32];
          #pragma unroll
          for (int g = 0; g < 4; ++g) {
            acc[t][g] = __builtin_amdgcn_mfma_f32_16x16x32_f16(af0, bfr[g][0], acc[t][g], 0, 0, 0);
            acc[t][g] = __builtin_amdgcn_mfma_f32_16x16x32_f16(af1, bfr[g][1], acc[t][g], 0, 0, 0);
          }
        }
      }
    }

    // ---- Phase B: 16 sequential steps ----
    #pragma unroll
    for (int s = 0; s < TC; ++s) {
      const int st   = cc * TC + s;
      const int half = s & 1;   // which M-tile half (rows half*8..half*8+8) is this step
      f16x8 ah0 = (f16x8){0, 0, 0, 0, 0, 0, 0, 0};
      f16x8 ah1 = (f16x8){0, 0, 0, 0, 0, 0, 0, 0};
      if ((ln >> 3) == half) {   // A-frag rows of the valid half carry h, others zero
        const _Float16* hr = &hbuf[st & 1][ln & 7][0];
        ah0 = *(const f16x8*)(hr + kg * 8);
        ah1 = *(const f16x8*)(hr + kg * 8 + 32);
      }
      f32x4 gf[4];
      #pragma unroll
      for (int g = 0; g < 4; ++g) {
        gf[g] = __builtin_amdgcn_mfma_f32_16x16x32_f16(ah0, whhf[g][0], acc[s >> 1][g], 0, 0, 0);
        gf[g] = __builtin_amdgcn_mfma_f32_16x16x32_f16(ah1, whhf[g][1], gf[g], 0, 0, 0);
      }
      if ((kg >> 1) == half) {   // C rows kg*4+r fall in this step's half
        const int b0 = (kg & 1) * 4;
        #pragma unroll
        for (int r = 0; r < 4; ++r) {
          const float iv = sigm(gf[0][r] + bsum[0]);
          const float fv = sigm(gf[1][r] + bsum[1]);
          const float gv = tanh_f(gf[2][r] + bsum[2]);
          const float ov = sigm(gf[3][r] + bsum[3]);
          const float cn = fv * cb[b0 + r][u] + iv * gv;
          cb[b0 + r][u] = cn;
          const float hn = ov * tanh_f(cn);
          hbuf[(st + 1) & 1][b0 + r][u] = (_Float16)hn;
          if (st == T_SZ - 1) h32[b0 + r][u] = hn;
        }
      }
      __syncthreads();   // h/c writes visible; also protects Ax restaging next chunk
    }
  }

  // ---- FC head ----
  if (tid < 16) {
    const int r = tid >> 1, j = tid & 1;
    float a = bfc[j];
    #pragma unroll
    for (int uu = 0; uu < 64; ++uu) a += h32[r][uu] * Wfc[j * 64 + uu];
    out[(size_t)(br0 + r) * 2 + j] = a;
  }
}

extern "C" void kernel_launch(void* const* d_in, const int* in_sizes, int n_in,
                              void* d_out, int out_size, void* d_ws, size_t ws_size,
                              hipStream_t stream) {
  const float* x   = (const float*)d_in[0];
  const float* Wih = (const float*)d_in[1];
  const float* Whh = (const float*)d_in[2];
  const float* bih = (const float*)d_in[3];
  const float* bhh = (const float*)d_in[4];
  const float* Wfc = (const float*)d_in[5];
  const float* bfc = (const float*)d_in[6];
  float* out = (float*)d_out;
  lstm_fused<<<dim3(B_SZ / BR), dim3(256), 0, stream>>>(x, Wih, Whh, bih, bhh, Wfc, bfc, out);
}

// Round 3
// 225.691 us; speedup vs baseline: 1.2283x; 1.1336x over previous
//
#include <hip/hip_runtime.h>

#define B_SZ 4096
#define T_SZ 64
#define F_SZ 512
#define H_SZ 64
#define BR 8                  // batch rows per block -> 512 blocks
#define TC 8                  // timesteps per chunk
#define NCHUNK (T_SZ / TC)    // 8
#define NTILE 64              // total K-tiles: 8 chunks * 8 kk
#define WIH_HALF_ELEMS (256 * 512)

typedef _Float16 f16x8 __attribute__((ext_vector_type(8)));
typedef float f32x4 __attribute__((ext_vector_type(4)));

__device__ __forceinline__ float fast_rcp(float x) { return __builtin_amdgcn_rcpf(x); }
__device__ __forceinline__ float sigm(float x) { return fast_rcp(1.0f + __expf(-x)); }
__device__ __forceinline__ float tanh_f(float x) {
  x = fminf(15.0f, fmaxf(-15.0f, x));
  float e = __expf(2.0f * x);
  return (e - 1.0f) * fast_rcp(e + 1.0f);
}
__device__ __forceinline__ f16x8 cvt8(float4 a, float4 b) {
  f16x8 h;
  h[0] = (_Float16)a.x; h[1] = (_Float16)a.y; h[2] = (_Float16)a.z; h[3] = (_Float16)a.w;
  h[4] = (_Float16)b.x; h[5] = (_Float16)b.y; h[6] = (_Float16)b.z; h[7] = (_Float16)b.w;
  return h;
}

// Pre-transcode Wih (131072) and Whh (16384) fp32 -> fp16 into d_ws.
__global__ void transcode_f16(const float* __restrict__ Wih, const float* __restrict__ Whh,
                              _Float16* __restrict__ ws) {
  const int i4 = (blockIdx.x * 256 + threadIdx.x) * 4;
  if (i4 < WIH_HALF_ELEMS) {
    float4 v = *(const float4*)(Wih + i4);
    ws[i4] = (_Float16)v.x; ws[i4+1] = (_Float16)v.y; ws[i4+2] = (_Float16)v.z; ws[i4+3] = (_Float16)v.w;
  } else {
    const int j4 = i4 - WIH_HALF_ELEMS;
    float4 v = *(const float4*)(Whh + j4);
    _Float16* w2 = ws + WIH_HALF_ELEMS;
    w2[j4] = (_Float16)v.x; w2[j4+1] = (_Float16)v.y; w2[j4+2] = (_Float16)v.z; w2[j4+3] = (_Float16)v.w;
  }
}

// Fused LSTM, continuous-streaming phase A:
//  - x staged fp32 via global_load_lds into a 4-slot ring of 16KB K-tiles (64 mrows x 64 k).
//  - counted s_waitcnt vmcnt(8) + raw s_barrier per tile; 3 tiles (48KB) always in flight,
//    including across phase B (raw barriers never drain vmcnt).
//  - both-sides XOR swizzle: global SOURCE pre-swizzled per-lane (LDS dest linear as
//    global_load_lds requires), ds_read address swizzled identically -> no bank conflicts.
//  - fp32->fp16 conversion at fragment read; Wih/Whh B-frags are 16B fp16 loads from d_ws.
__global__ __launch_bounds__(256, 2)
void lstm_fused(const float* __restrict__ x, const _Float16* __restrict__ ws,
                const float* __restrict__ bih, const float* __restrict__ bhh,
                const float* __restrict__ Wfc, const float* __restrict__ bfc,
                float* __restrict__ out)
{
  __shared__ __align__(16) float Ax[4][64 * 64];      // 4-slot ring, tile = 64 mrows x 64 k fp32
  __shared__ __align__(16) _Float16 hbuf[2][8][72];   // h double buffer
  __shared__ float cb[8][64];
  __shared__ float h32[8][64];

  const int tid  = threadIdx.x;
  const int wv   = tid >> 6;
  const int lane = tid & 63;
  const int ln   = lane & 15;
  const int kg   = lane >> 4;
  const int br0  = blockIdx.x * BR;
  const int u    = wv * 16 + ln;

  const _Float16* Wihh = ws;                       // [256][512] fp16
  const _Float16* Whhh = ws + WIH_HALF_ELEMS;      // [256][64]  fp16

  for (int i = tid; i < 8 * 72; i += 256) (&hbuf[0][0][0])[i] = (_Float16)0.0f;
  for (int i = tid; i < 8 * 64; i += 256) (&cb[0][0])[i] = 0.0f;
  __syncthreads();

  // Whh B-fragments pinned in registers for all 64 steps.
  f16x8 whhf[4][2];
  #pragma unroll
  for (int g = 0; g < 4; ++g)
    #pragma unroll
    for (int k2 = 0; k2 < 2; ++k2)
      whhf[g][k2] = *(const f16x8*)(Whhh + (size_t)((g * 4 + wv) * 16 + ln) * H_SZ
                                         + kg * 8 + k2 * 32);

  float bsum[4];
  #pragma unroll
  for (int g = 0; g < 4; ++g) bsum[g] = bih[g * 64 + u] + bhh[g * 64 + u];

  // ---- tile DMA issue: wave wv issues instrs i = wv*4+j; each instr = 1KB = 4 mrows ----
  // lane l of instr i -> mrow m = 4i + (l>>4), LDS word-in-row (l&15)*4 (linear dest);
  // SOURCE word = ((l&15)*4) ^ ((m&7)<<2)  => LDS[m][w] holds x[m][w ^ ((m&7)<<2)].
  auto issue_tile = [&](int tau) {
    if (tau >= NTILE + 2) return;
    const int tc   = tau < NTILE ? tau : NTILE - 1;   // dummies 64,65 reload tile 63
    const int cc   = tc >> 3, kk = tc & 7, slot = tau & 3;
    #pragma unroll
    for (int j = 0; j < 4; ++j) {
      const int i = wv * 4 + j;
      const int m = i * 4 + (lane >> 4);
      const int kw = (((lane & 15) << 2) ^ ((m & 7) << 2));
      const float* gp = x + (size_t)(br0 + (m & 7)) * (T_SZ * F_SZ)
                          + (size_t)(cc * TC + (m >> 3)) * F_SZ + kk * 64 + kw;
      __builtin_amdgcn_global_load_lds(gp, &Ax[slot][i * 256], 16, 0, 0);
    }
  };

  // Prologue: 3 tiles in flight.
  issue_tile(0); issue_tile(1); issue_tile(2);

  const int sw = (ln & 7) << 2;   // read-side swizzle (m&7 == ln&7 for m = t*16+ln)

  for (int cc = 0; cc < NCHUNK; ++cc) {
    f32x4 acc[4][4];
    #pragma unroll
    for (int t = 0; t < 4; ++t)
      #pragma unroll
      for (int g = 0; g < 4; ++g) acc[t][g] = (f32x4){0.0f, 0.0f, 0.0f, 0.0f};

    // ---- Phase A: 8 K-tiles; tile T ready after vmcnt(8)+barrier; issue T+3 ----
    for (int kk = 0; kk < 8; ++kk) {
      const int tau = cc * 8 + kk;
      asm volatile("s_waitcnt vmcnt(8)" ::: "memory");   // tile tau landed (tau+1,tau+2 in flight)
      __builtin_amdgcn_s_barrier();                       // all waves' quarters landed
      issue_tile(tau + 3);                                // into slot (tau-1)&3: reads retired

      // B-fragments: direct 16B fp16 loads (L1/L2-resident)
      f16x8 bfr[4][2];
      #pragma unroll
      for (int g = 0; g < 4; ++g)
        #pragma unroll
        for (int k2 = 0; k2 < 2; ++k2)
          bfr[g][k2] = *(const f16x8*)(Wihh + (size_t)((g * 4 + wv) * 16 + ln) * F_SZ
                                            + tau % 8 * 0 + kk * 64 + kg * 8 + k2 * 32);

      const float* axs = &Ax[tau & 3][0];
      #pragma unroll
      for (int t = 0; t < 4; ++t) {
        const int rb = (t * 16 + ln) * 64;
        const int w00 = (kg * 8) ^ sw;
        float4 a0 = *(const float4*)(axs + rb + w00);
        float4 a1 = *(const float4*)(axs + rb + (w00 ^ 4));
        float4 a2 = *(const float4*)(axs + rb + 32 + w00);
        float4 a3 = *(const float4*)(axs + rb + 32 + (w00 ^ 4));
        f16x8 af0 = cvt8(a0, a1);
        f16x8 af1 = cvt8(a2, a3);
        #pragma unroll
        for (int g = 0; g < 4; ++g) {
          acc[t][g] = __builtin_amdgcn_mfma_f32_16x16x32_f16(af0, bfr[g][0], acc[t][g], 0, 0, 0);
          acc[t][g] = __builtin_amdgcn_mfma_f32_16x16x32_f16(af1, bfr[g][1], acc[t][g], 0, 0, 0);
        }
      }
    }

    // ---- Phase B: 8 sequential steps (raw barriers; DMA for next chunk stays in flight) ----
    #pragma unroll
    for (int s = 0; s < TC; ++s) {
      const int st   = cc * TC + s;
      const int half = s & 1;
      f16x8 ah0 = (f16x8){0, 0, 0, 0, 0, 0, 0, 0};
      f16x8 ah1 = (f16x8){0, 0, 0, 0, 0, 0, 0, 0};
      if ((ln >> 3) == half) {
        const _Float16* hr = &hbuf[st & 1][ln & 7][0];
        ah0 = *(const f16x8*)(hr + kg * 8);
        ah1 = *(const f16x8*)(hr + kg * 8 + 32);
      }
      f32x4 gf[4];
      #pragma unroll
      for (int g = 0; g < 4; ++g) {
        gf[g] = __builtin_amdgcn_mfma_f32_16x16x32_f16(ah0, whhf[g][0], acc[s >> 1][g], 0, 0, 0);
        gf[g] = __builtin_amdgcn_mfma_f32_16x16x32_f16(ah1, whhf[g][1], gf[g], 0, 0, 0);
      }
      if ((kg >> 1) == half) {
        const int b0 = (kg & 1) * 4;
        #pragma unroll
        for (int r = 0; r < 4; ++r) {
          const float iv = sigm(gf[0][r] + bsum[0]);
          const float fv = sigm(gf[1][r] + bsum[1]);
          const float gv = tanh_f(gf[2][r] + bsum[2]);
          const float ov = sigm(gf[3][r] + bsum[3]);
          const float cn = fv * cb[b0 + r][u] + iv * gv;
          cb[b0 + r][u] = cn;
          const float hn = ov * tanh_f(cn);
          hbuf[(st + 1) & 1][b0 + r][u] = (_Float16)hn;
          if (st == T_SZ - 1) h32[b0 + r][u] = hn;
        }
      }
      asm volatile("s_waitcnt lgkmcnt(0)" ::: "memory");  // h/c LDS writes retired
      __builtin_amdgcn_s_barrier();                        // NO vmcnt drain here
    }
  }

  __syncthreads();   // end: full drain is fine
  if (tid < 16) {
    const int r = tid >> 1, j = tid & 1;
    float a = bfc[j];
    #pragma unroll
    for (int uu = 0; uu < 64; ++uu) a += h32[r][uu] * Wfc[j * 64 + uu];
    out[(size_t)(br0 + r) * 2 + j] = a;
  }
}

extern "C" void kernel_launch(void* const* d_in, const int* in_sizes, int n_in,
                              void* d_out, int out_size, void* d_ws, size_t ws_size,
                              hipStream_t stream) {
  const float* x   = (const float*)d_in[0];
  const float* Wih = (const float*)d_in[1];
  const float* Whh = (const float*)d_in[2];
  const float* bih = (const float*)d_in[3];
  const float* bhh = (const float*)d_in[4];
  const float* Wfc = (const float*)d_in[5];
  const float* bfc = (const float*)d_in[6];
  float* out = (float*)d_out;
  _Float16* ws = (_Float16*)d_ws;   // needs 288KB; harness scratch is MBs

  // (131072 + 16384) / 4 elems per thread / 256 threads = 144 blocks
  transcode_f16<<<dim3(144), dim3(256), 0, stream>>>(Wih, Whh, ws);
  lstm_fused<<<dim3(B_SZ / BR), dim3(256), 0, stream>>>(x, ws, bih, bhh, Wfc, bfc, out);
}

// Round 4
// 207.189 us; speedup vs baseline: 1.3380x; 1.0893x over previous
//
#include <hip/hip_runtime.h>

#define B_SZ 4096
#define T_SZ 64
#define F_SZ 512
#define H_SZ 64
#define BR 8                  // batch rows per block -> 512 blocks, 2 blocks/CU
#define TC 8                  // timesteps per chunk
#define NCHUNK (T_SZ / TC)    // 8
#define NTILE 64              // total K-tiles (8 chunks * 8)
#define WIH_HALF_ELEMS (256 * 512)

typedef _Float16 f16x8 __attribute__((ext_vector_type(8)));
typedef float f32x4 __attribute__((ext_vector_type(4)));

__device__ __forceinline__ float fast_rcp(float x) { return __builtin_amdgcn_rcpf(x); }
__device__ __forceinline__ float sigm(float x) { return fast_rcp(1.0f + __expf(-x)); }
__device__ __forceinline__ float tanh_f(float x) {
  x = fminf(15.0f, fmaxf(-15.0f, x));
  float e = __expf(2.0f * x);
  return (e - 1.0f) * fast_rcp(e + 1.0f);
}
__device__ __forceinline__ f16x8 cvt8(float4 a, float4 b) {
  f16x8 h;
  h[0] = (_Float16)a.x; h[1] = (_Float16)a.y; h[2] = (_Float16)a.z; h[3] = (_Float16)a.w;
  h[4] = (_Float16)b.x; h[5] = (_Float16)b.y; h[6] = (_Float16)b.z; h[7] = (_Float16)b.w;
  return h;
}

// Pre-transcode Wih (131072) and Whh (16384) fp32 -> fp16 into d_ws.
__global__ void transcode_f16(const float* __restrict__ Wih, const float* __restrict__ Whh,
                              _Float16* __restrict__ ws) {
  const int i4 = (blockIdx.x * 256 + threadIdx.x) * 4;
  if (i4 < WIH_HALF_ELEMS) {
    float4 v = *(const float4*)(Wih + i4);
    ws[i4] = (_Float16)v.x; ws[i4+1] = (_Float16)v.y; ws[i4+2] = (_Float16)v.z; ws[i4+3] = (_Float16)v.w;
  } else {
    const int j4 = i4 - WIH_HALF_ELEMS;
    float4 v = *(const float4*)(Whh + j4);
    _Float16* w2 = ws + WIH_HALF_ELEMS;
    w2[j4] = (_Float16)v.x; w2[j4+1] = (_Float16)v.y; w2[j4+2] = (_Float16)v.z; w2[j4+3] = (_Float16)v.w;
  }
}

// Fused LSTM with a truly-continuous DMA ring:
//  - x staged fp32 via global_load_lds, 4-slot ring of 16KB tiles, counted vmcnt only
//    (never 0 in the loop), raw s_barrier.
//  - Wih B-fragments DOUBLE-BUFFERED in registers: B(kk+1) prefetched during iter kk,
//    consumed at iter kk+1. The compiler's wait for B(kk) is then vmcnt(16), and
//    in-order retirement of B(kk) (issued after D(tau+1)) guarantees tile tau+1 has
//    landed one iteration before its reads -- no vmcnt(0) anywhere in the main loop.
//  - both-sides XOR swizzle: pre-swizzled global SOURCE per-lane (linear LDS dest as
//    global_load_lds requires) + identical swizzle on ds_read -> conflict-free.
__global__ __launch_bounds__(256, 2)
void lstm_fused(const float* __restrict__ x, const _Float16* __restrict__ ws,
                const float* __restrict__ bih, const float* __restrict__ bhh,
                const float* __restrict__ Wfc, const float* __restrict__ bfc,
                float* __restrict__ out)
{
  __shared__ __align__(16) float Ax[4][64 * 64];      // ring: tile = 64 mrows x 64 k fp32
  __shared__ __align__(16) _Float16 hbuf[2][8][72];
  __shared__ float cb[8][64];
  __shared__ float h32[8][64];

  const int tid  = threadIdx.x;
  const int wv   = tid >> 6;
  const int lane = tid & 63;
  const int ln   = lane & 15;
  const int kg   = lane >> 4;
  const int br0  = blockIdx.x * BR;
  const int u    = wv * 16 + ln;

  const _Float16* Wihh = ws;                       // [256][512] fp16
  const _Float16* Whhh = ws + WIH_HALF_ELEMS;      // [256][64]  fp16

  for (int i = tid; i < 8 * 72; i += 256) (&hbuf[0][0][0])[i] = (_Float16)0.0f;
  for (int i = tid; i < 8 * 64; i += 256) (&cb[0][0])[i] = 0.0f;
  __syncthreads();

  f16x8 whhf[4][2];
  #pragma unroll
  for (int g = 0; g < 4; ++g)
    #pragma unroll
    for (int k2 = 0; k2 < 2; ++k2)
      whhf[g][k2] = *(const f16x8*)(Whhh + (size_t)((g * 4 + wv) * 16 + ln) * H_SZ
                                         + kg * 8 + k2 * 32);

  float bsum[4];
  #pragma unroll
  for (int g = 0; g < 4; ++g) bsum[g] = bih[g * 64 + u] + bhh[g * 64 + u];

  // DMA issue: wave wv issues 4 instr; lane l of instr i -> mrow m = 4i + (l>>4),
  // linear LDS word (l&15)*4; SOURCE word XOR'd by ((m&7)<<2).
  auto issue_tile = [&](int tau) {
    if (tau >= NTILE) return;                    // tail: just let the queue shrink
    const int cc = tau >> 3, kk = tau & 7, slot = tau & 3;
    #pragma unroll
    for (int j = 0; j < 4; ++j) {
      const int i = wv * 4 + j;
      const int m = i * 4 + (lane >> 4);
      const int kw = (((lane & 15) << 2) ^ ((m & 7) << 2));
      const float* gp = x + (size_t)(br0 + (m & 7)) * (T_SZ * F_SZ)
                          + (size_t)(cc * TC + (m >> 3)) * F_SZ + kk * 64 + kw;
      __builtin_amdgcn_global_load_lds(gp, &Ax[slot][i * 256], 16, 0, 0);
    }
  };

  auto load_bfr = [&](f16x8 (&b)[4][2], int kk) {
    #pragma unroll
    for (int g = 0; g < 4; ++g)
      #pragma unroll
      for (int k2 = 0; k2 < 2; ++k2)
        b[g][k2] = *(const f16x8*)(Wihh + (size_t)((g * 4 + wv) * 16 + ln) * F_SZ
                                        + kk * 64 + kg * 8 + k2 * 32);
  };

  f32x4 acc[4][4];
  const int sw = (ln & 7) << 2;

  // One phase-A iteration: consume bcon (loaded last iter), prefetch bpre for next.
  auto phaseA_iter = [&](int tau, f16x8 (&bcon)[4][2], f16x8 (&bpre)[4][2]) {
    asm volatile("s_waitcnt vmcnt(16)" ::: "memory");  // transient guard (iter 0: lands D0)
    __builtin_amdgcn_s_barrier();                      // tile tau ready for all waves
    load_bfr(bpre, (tau + 1) & 7);                     // B first (keeps D retirement minimal)
    issue_tile(tau + 3);                               // into slot (tau-1)&3: reads done
    asm volatile("" ::: "memory");                     // pin VMEM issue order
    const float* axs = &Ax[tau & 3][0];
    #pragma unroll
    for (int t = 0; t < 4; ++t) {
      const int rb  = (t * 16 + ln) * 64;
      const int w00 = (kg * 8) ^ sw;
      float4 a0 = *(const float4*)(axs + rb + w00);
      float4 a1 = *(const float4*)(axs + rb + (w00 ^ 4));
      float4 a2 = *(const float4*)(axs + rb + 32 + w00);
      float4 a3 = *(const float4*)(axs + rb + 32 + (w00 ^ 4));
      f16x8 af0 = cvt8(a0, a1);
      f16x8 af1 = cvt8(a2, a3);
      #pragma unroll
      for (int g = 0; g < 4; ++g) {
        acc[t][g] = __builtin_amdgcn_mfma_f32_16x16x32_f16(af0, bcon[g][0], acc[t][g], 0, 0, 0);
        acc[t][g] = __builtin_amdgcn_mfma_f32_16x16x32_f16(af1, bcon[g][1], acc[t][g], 0, 0, 0);
      }
    }
  };

  // Prologue: 3 DMA tiles in flight (oldest), then B(0) into bA.
  issue_tile(0); issue_tile(1); issue_tile(2);
  asm volatile("" ::: "memory");                 // D0..D2 strictly before B0 in the queue
  f16x8 bA[4][2], bB[4][2];
  load_bfr(bA, 0);

  for (int cc = 0; cc < NCHUNK; ++cc) {
    #pragma unroll
    for (int t = 0; t < 4; ++t)
      #pragma unroll
      for (int g = 0; g < 4; ++g) acc[t][g] = (f32x4){0.0f, 0.0f, 0.0f, 0.0f};

    // ---- Phase A: 8 K-tiles, B-fragment double buffer alternating bA/bB ----
    #pragma unroll
    for (int kp = 0; kp < 4; ++kp) {
      phaseA_iter(cc * 8 + 2 * kp,     bA, bB);
      phaseA_iter(cc * 8 + 2 * kp + 1, bB, bA);
    }
    // after kp loop, bA holds B(0) for the next chunk

    // ---- Phase B: 8 sequential steps; raw barriers, DMA stays in flight ----
    #pragma unroll
    for (int s = 0; s < TC; ++s) {
      const int st   = cc * TC + s;
      const int half = s & 1;
      f16x8 ah0 = (f16x8){0, 0, 0, 0, 0, 0, 0, 0};
      f16x8 ah1 = (f16x8){0, 0, 0, 0, 0, 0, 0, 0};
      if ((ln >> 3) == half) {
        const _Float16* hr = &hbuf[st & 1][ln & 7][0];
        ah0 = *(const f16x8*)(hr + kg * 8);
        ah1 = *(const f16x8*)(hr + kg * 8 + 32);
      }
      f32x4 gf[4];
      #pragma unroll
      for (int g = 0; g < 4; ++g) {
        gf[g] = __builtin_amdgcn_mfma_f32_16x16x32_f16(ah0, whhf[g][0], acc[s >> 1][g], 0, 0, 0);
        gf[g] = __builtin_amdgcn_mfma_f32_16x16x32_f16(ah1, whhf[g][1], gf[g], 0, 0, 0);
      }
      if ((kg >> 1) == half) {
        const int b0 = (kg & 1) * 4;
        #pragma unroll
        for (int r = 0; r < 4; ++r) {
          const float iv = sigm(gf[0][r] + bsum[0]);
          const float fv = sigm(gf[1][r] + bsum[1]);
          const float gv = tanh_f(gf[2][r] + bsum[2]);
          const float ov = sigm(gf[3][r] + bsum[3]);
          const float cn = fv * cb[b0 + r][u] + iv * gv;
          cb[b0 + r][u] = cn;
          const float hn = ov * tanh_f(cn);
          hbuf[(st + 1) & 1][b0 + r][u] = (_Float16)hn;
          if (st == T_SZ - 1) h32[b0 + r][u] = hn;
        }
      }
      asm volatile("s_waitcnt lgkmcnt(0)" ::: "memory");
      __builtin_amdgcn_s_barrier();               // NO vmcnt drain here
    }
  }

  __syncthreads();   // epilogue: full drain is fine
  if (tid < 16) {
    const int r = tid >> 1, j = tid & 1;
    float a = bfc[j];
    #pragma unroll
    for (int uu = 0; uu < 64; ++uu) a += h32[r][uu] * Wfc[j * 64 + uu];
    out[(size_t)(br0 + r) * 2 + j] = a;
  }
}

extern "C" void kernel_launch(void* const* d_in, const int* in_sizes, int n_in,
                              void* d_out, int out_size, void* d_ws, size_t ws_size,
                              hipStream_t stream) {
  const float* x   = (const float*)d_in[0];
  const float* Wih = (const float*)d_in[1];
  const float* Whh = (const float*)d_in[2];
  const float* bih = (const float*)d_in[3];
  const float* bhh = (const float*)d_in[4];
  const float* Wfc = (const float*)d_in[5];
  const float* bfc = (const float*)d_in[6];
  float* out = (float*)d_out;
  _Float16* ws = (_Float16*)d_ws;   // 288KB used

  transcode_f16<<<dim3(144), dim3(256), 0, stream>>>(Wih, Whh, ws);
  lstm_fused<<<dim3(B_SZ / BR), dim3(256), 0, stream>>>(x, ws, bih, bhh, Wfc, bfc, out);
}